// Round 1
// baseline (20.359 us; speedup 1.0000x reference)
//
#include <hip/hip_runtime.h>

#define N_SRC 100000
#define M_NODES 20000
#define K_NEI 32
#define H_DIM 128
#define NEG_SLOPE 0.01f

// One fused kernel.
// Block = 256 threads = 4 waves. Each wave processes 2 m's:
//   lanes 0-31 -> m = base + wave*2 + 0, lanes 32-63 -> m = base + wave*2 + 1
// Within a 32-lane half, lane index = neighbor k (K=32).
// Source embeddings are regenerated from the scalar h[i] on the fly:
//   emb[j] = relu(h_i * wl[j] + bl[j])
__global__ __launch_bounds__(256) void intra_att_kernel(
    const int*   __restrict__ nei,        // (M, K)
    const float* __restrict__ h,          // (N_SRC, 1)
    const float* __restrict__ h_refer,    // (M, 1)
    const float* __restrict__ map_l_w,    // (H, 1)
    const float* __restrict__ map_l_b,    // (H,)
    const float* __restrict__ map_r_w,    // (H, 1)
    const float* __restrict__ map_r_b,    // (H,)
    const float* __restrict__ att_inter,  // (1, 2H): [a_ref | a_nei]
    float*       __restrict__ out,        // (M,)
    float*       __restrict__ att)        // (M, K)
{
    __shared__ float s_wl[H_DIM];
    __shared__ float s_bl[H_DIM];
    __shared__ float s_an[H_DIM];       // a_nei
    __shared__ float s_hr[8][H_DIM];    // 4 waves * 2 m's

    const int tid = threadIdx.x;

    // Stage the m-independent constants once per block.
    if (tid < H_DIM) {
        s_wl[tid] = map_l_w[tid];
        s_bl[tid] = map_l_b[tid];
        s_an[tid] = att_inter[H_DIM + tid];
    }

    const int wave  = tid >> 6;
    const int lane  = tid & 63;
    const int half  = lane >> 5;        // which m within the wave
    const int l32   = lane & 31;        // k index / j-group id
    const int mslot = wave * 2 + half;  // 0..7
    const int m     = blockIdx.x * 8 + mslot;
    const bool valid = (m < M_NODES);

    __syncthreads();

    // ---- per-m: hr[j] = relu(h_refer[m]*wr[j] + br[j]); hrdot = hr . a_ref ----
    float hrdot = 0.f;
    {
        const float hrefm = valid ? h_refer[m] : 0.f;
        const int j = l32 * 4;
        const float4 wr4 = *(const float4*)(map_r_w + j);
        const float4 br4 = *(const float4*)(map_r_b + j);
        const float4 ar4 = *(const float4*)(att_inter + j);   // a_ref
        float4 hr4;
        hr4.x = fmaxf(0.f, fmaf(hrefm, wr4.x, br4.x));
        hr4.y = fmaxf(0.f, fmaf(hrefm, wr4.y, br4.y));
        hr4.z = fmaxf(0.f, fmaf(hrefm, wr4.z, br4.z));
        hr4.w = fmaxf(0.f, fmaf(hrefm, wr4.w, br4.w));
        *(float4*)(&s_hr[mslot][j]) = hr4;
        hrdot = hr4.x*ar4.x + hr4.y*ar4.y + hr4.z*ar4.z + hr4.w*ar4.w;
        // reduce across the 32-lane half (masks <=16 stay within the half)
        #pragma unroll
        for (int o = 16; o >= 1; o >>= 1) hrdot += __shfl_xor(hrdot, o);
    }
    __syncthreads();   // s_hr visible (also cheap safety for the const stage)

    // ---- per (m, k): gather scalar, regenerate emb, two serial dots ----
    float logit = 0.f;   // emb . a_nei
    float inner = 0.f;   // emb . hr
    if (valid) {
        const int   idx = nei[m * K_NEI + l32];
        const float h_i = h[idx];
        const float* hrp = s_hr[mslot];
        #pragma unroll 8
        for (int j = 0; j < H_DIM; j += 4) {
            const float4 wl4 = *(const float4*)(s_wl + j);
            const float4 bl4 = *(const float4*)(s_bl + j);
            const float4 an4 = *(const float4*)(s_an + j);
            const float4 hr4 = *(const float4*)(hrp + j);
            const float e0 = fmaxf(0.f, fmaf(h_i, wl4.x, bl4.x));
            const float e1 = fmaxf(0.f, fmaf(h_i, wl4.y, bl4.y));
            const float e2 = fmaxf(0.f, fmaf(h_i, wl4.z, bl4.z));
            const float e3 = fmaxf(0.f, fmaf(h_i, wl4.w, bl4.w));
            logit = fmaf(e0, an4.x, logit);
            logit = fmaf(e1, an4.y, logit);
            logit = fmaf(e2, an4.z, logit);
            logit = fmaf(e3, an4.w, logit);
            inner = fmaf(e0, hr4.x, inner);
            inner = fmaf(e1, hr4.y, inner);
            inner = fmaf(e2, hr4.z, inner);
            inner = fmaf(e3, hr4.w, inner);
        }
    }
    logit += hrdot;
    // leaky relu
    logit = (logit >= 0.f) ? logit : NEG_SLOPE * logit;

    // ---- softmax over k (32 lanes) + weighted sum, fused ----
    float wmax = logit;
    #pragma unroll
    for (int o = 16; o >= 1; o >>= 1) wmax = fmaxf(wmax, __shfl_xor(wmax, o));
    const float e = expf(logit - wmax);
    float se  = e;           // sum of exp
    float sei = e * inner;   // sum of exp * lr_inner
    #pragma unroll
    for (int o = 16; o >= 1; o >>= 1) {
        se  += __shfl_xor(se,  o);
        sei += __shfl_xor(sei, o);
    }

    if (valid) {
        att[m * K_NEI + l32] = e / se;
        if (l32 == 0) out[m] = fmaxf(0.f, sei / se);
    }
}

extern "C" void kernel_launch(void* const* d_in, const int* in_sizes, int n_in,
                              void* d_out, int out_size, void* d_ws, size_t ws_size,
                              hipStream_t stream) {
    const int*   nei       = (const int*)  d_in[0];
    const float* h         = (const float*)d_in[1];
    const float* h_refer   = (const float*)d_in[2];
    const float* map_l_w   = (const float*)d_in[3];
    const float* map_l_b   = (const float*)d_in[4];
    const float* map_r_w   = (const float*)d_in[5];
    const float* map_r_b   = (const float*)d_in[6];
    const float* att_inter = (const float*)d_in[7];

    float* out = (float*)d_out;          // (M,)
    float* att = out + M_NODES;          // (M, K)

    const int blocks = (M_NODES + 7) / 8;   // 8 m's per block
    intra_att_kernel<<<blocks, 256, 0, stream>>>(
        nei, h, h_refer, map_l_w, map_l_b, map_r_w, map_r_b, att_inter,
        out, att);
}

// Round 2
// 19.029 us; speedup vs baseline: 1.0699x; 1.0699x over previous
//
#include <hip/hip_runtime.h>

#define N_SRC 100000
#define M_NODES 20000
#define K_NEI 32
#define H_DIM 128
#define NEG_SLOPE 0.01f

#define BLK_M 32          // m's per block
#define HR_PAD 132        // 128 + 4 pad -> 8 wave-rows spread over all 32 banks

// Block = 256 threads. Each m is handled by 8 consecutive threads (sub = tid&7),
// each thread owning 4 neighbors (k = sub*4 .. sub*4+3). 32 m's per block.
// Source embeddings regenerated from the scalar h[i]: emb[j]=relu(h_i*wl[j]+bl[j]).
// One LDS read-set (wl,bl,an,hr float4) now feeds 4 tasks -> VALU-bound.
__global__ __launch_bounds__(256) void intra_att_kernel(
    const int*   __restrict__ nei,        // (M, K)
    const float* __restrict__ h,          // (N_SRC, 1)
    const float* __restrict__ h_refer,    // (M, 1)
    const float* __restrict__ map_l_w,    // (H, 1)
    const float* __restrict__ map_l_b,    // (H,)
    const float* __restrict__ map_r_w,    // (H, 1)
    const float* __restrict__ map_r_b,    // (H,)
    const float* __restrict__ att_inter,  // (1, 2H): [a_ref | a_nei]
    float*       __restrict__ out,        // (M,)
    float*       __restrict__ att)        // (M, K)
{
    __shared__ __attribute__((aligned(16))) float s_wl[H_DIM];
    __shared__ __attribute__((aligned(16))) float s_bl[H_DIM];
    __shared__ __attribute__((aligned(16))) float s_an[H_DIM];
    __shared__ __attribute__((aligned(16))) float s_hr[BLK_M][HR_PAD];

    const int tid  = threadIdx.x;
    const int slot = tid >> 3;          // 0..31 : which m in the block
    const int sub  = tid & 7;           // 0..7  : which k-quad
    const int m    = blockIdx.x * BLK_M + slot;   // grid is an exact fit

    // ---- issue gathers early (consumed after the hr phase) ----
    const int4 nv = *(const int4*)(nei + m * K_NEI + sub * 4);
    float h_i[4];
    h_i[0] = h[nv.x]; h_i[1] = h[nv.y]; h_i[2] = h[nv.z]; h_i[3] = h[nv.w];

    // ---- stage m-independent constants ----
    if (tid < H_DIM) {
        s_wl[tid] = map_l_w[tid];
        s_bl[tid] = map_l_b[tid];
        s_an[tid] = att_inter[H_DIM + tid];
    }

    // ---- hr phase: 8 threads per m, 16 j's each ----
    const float rm = h_refer[m];
    float hrdot = 0.f;
    {
        const int jb = sub * 16;
        #pragma unroll
        for (int c = 0; c < 16; c += 4) {
            const float4 wr4 = *(const float4*)(map_r_w + jb + c);
            const float4 br4 = *(const float4*)(map_r_b + jb + c);
            const float4 ar4 = *(const float4*)(att_inter + jb + c);  // a_ref
            float4 hr4;
            hr4.x = fmaxf(0.f, fmaf(rm, wr4.x, br4.x));
            hr4.y = fmaxf(0.f, fmaf(rm, wr4.y, br4.y));
            hr4.z = fmaxf(0.f, fmaf(rm, wr4.z, br4.z));
            hr4.w = fmaxf(0.f, fmaf(rm, wr4.w, br4.w));
            *(float4*)(&s_hr[slot][jb + c]) = hr4;
            hrdot += hr4.x*ar4.x + hr4.y*ar4.y + hr4.z*ar4.z + hr4.w*ar4.w;
        }
        // butterfly within the aligned 8-lane group
        #pragma unroll
        for (int o = 4; o >= 1; o >>= 1) hrdot += __shfl_xor(hrdot, o);
    }
    __syncthreads();

    // ---- main loop: 4 tasks share each LDS read-set ----
    float lg[4] = {0.f, 0.f, 0.f, 0.f};   // emb . a_nei
    float in_[4] = {0.f, 0.f, 0.f, 0.f};  // emb . hr
    const float* hrp = s_hr[slot];
    #pragma unroll 8
    for (int j = 0; j < H_DIM; j += 4) {
        const float4 wl4 = *(const float4*)(s_wl + j);
        const float4 bl4 = *(const float4*)(s_bl + j);
        const float4 an4 = *(const float4*)(s_an + j);
        const float4 hr4 = *(const float4*)(hrp + j);
        #pragma unroll
        for (int t = 0; t < 4; ++t) {
            const float hi = h_i[t];
            const float e0 = fmaxf(0.f, fmaf(hi, wl4.x, bl4.x));
            const float e1 = fmaxf(0.f, fmaf(hi, wl4.y, bl4.y));
            const float e2 = fmaxf(0.f, fmaf(hi, wl4.z, bl4.z));
            const float e3 = fmaxf(0.f, fmaf(hi, wl4.w, bl4.w));
            lg[t] = fmaf(e0, an4.x, lg[t]);
            lg[t] = fmaf(e1, an4.y, lg[t]);
            lg[t] = fmaf(e2, an4.z, lg[t]);
            lg[t] = fmaf(e3, an4.w, lg[t]);
            in_[t] = fmaf(e0, hr4.x, in_[t]);
            in_[t] = fmaf(e1, hr4.y, in_[t]);
            in_[t] = fmaf(e2, hr4.z, in_[t]);
            in_[t] = fmaf(e3, hr4.w, in_[t]);
        }
    }

    // ---- logits + leaky relu ----
    #pragma unroll
    for (int t = 0; t < 4; ++t) {
        float l = lg[t] + hrdot;
        lg[t] = (l >= 0.f) ? l : NEG_SLOPE * l;
    }

    // ---- softmax over 32 k's (4 local x 8 lanes) + weighted sum ----
    float mx = fmaxf(fmaxf(lg[0], lg[1]), fmaxf(lg[2], lg[3]));
    #pragma unroll
    for (int o = 4; o >= 1; o >>= 1) mx = fmaxf(mx, __shfl_xor(mx, o));

    float e[4];
    #pragma unroll
    for (int t = 0; t < 4; ++t) e[t] = __expf(lg[t] - mx);
    float se  = e[0] + e[1] + e[2] + e[3];
    float sei = e[0]*in_[0] + e[1]*in_[1] + e[2]*in_[2] + e[3]*in_[3];
    #pragma unroll
    for (int o = 4; o >= 1; o >>= 1) {
        se  += __shfl_xor(se,  o);
        sei += __shfl_xor(sei, o);
    }

    const float inv = 1.0f / se;
    float4 a4;
    a4.x = e[0] * inv; a4.y = e[1] * inv; a4.z = e[2] * inv; a4.w = e[3] * inv;
    *(float4*)(att + m * K_NEI + sub * 4) = a4;
    if (sub == 0) out[m] = fmaxf(0.f, sei * inv);
}

extern "C" void kernel_launch(void* const* d_in, const int* in_sizes, int n_in,
                              void* d_out, int out_size, void* d_ws, size_t ws_size,
                              hipStream_t stream) {
    const int*   nei       = (const int*)  d_in[0];
    const float* h         = (const float*)d_in[1];
    const float* h_refer   = (const float*)d_in[2];
    const float* map_l_w   = (const float*)d_in[3];
    const float* map_l_b   = (const float*)d_in[4];
    const float* map_r_w   = (const float*)d_in[5];
    const float* map_r_b   = (const float*)d_in[6];
    const float* att_inter = (const float*)d_in[7];

    float* out = (float*)d_out;          // (M,)
    float* att = out + M_NODES;          // (M, K)

    const int blocks = M_NODES / BLK_M;  // 625, exact fit
    intra_att_kernel<<<blocks, 256, 0, stream>>>(
        nei, h, h_refer, map_l_w, map_l_b, map_r_w, map_r_b, att_inter,
        out, att);
}